// Round 1
// baseline (2344.743 us; speedup 1.0000x reference)
//
#include <hip/hip_runtime.h>
#include <hip/hip_bf16.h>

typedef __bf16 bf16_t;
typedef __bf16 bf16x8 __attribute__((ext_vector_type(8)));
typedef __bf16 bf16x4 __attribute__((ext_vector_type(4)));
typedef float f32x4 __attribute__((ext_vector_type(4)));

#define LSTM_B 2048
#define LSTM_T 256
#define LSTM_H 256
#define LSTM_O 10
#define BTILE 16
#define NBLK (LSTM_B / BTILE)   // 128 blocks
#define THREADS 1024            // 16 waves; wave w owns hidden cols [w*16, w*16+16)

__device__ __forceinline__ float sigmoid_f(float x) {
    return 1.0f / (1.0f + __expf(-x));
}
// safe at both extremes: exp(-2x)->inf gives -1, ->0 gives +1 (no NaN)
__device__ __forceinline__ float tanh_f(float x) {
    return 2.0f / (1.0f + __expf(-2.0f * x)) - 1.0f;
}

// swizzled element index into h_sh [16][256] bf16: XOR bits 3..5 with row&7
// (byte-level: ^((r&7)<<4)) -> A-frag ds_read_b128 goes 16-way -> 2-way conflict
__device__ __forceinline__ int hsw(int r, int k) {
    return (r * 256 + k) ^ ((r & 7) << 3);
}

__global__ void __launch_bounds__(256) cast_wh_kernel(const float* __restrict__ Wh,
                                                      bf16_t* __restrict__ W2) {
    int idx = (blockIdx.x * 256 + threadIdx.x) * 4;
    float4 v = *(const float4*)(Wh + idx);
    bf16x4 o = {(bf16_t)v.x, (bf16_t)v.y, (bf16_t)v.z, (bf16_t)v.w};
    *(bf16x4*)(W2 + idx) = o;
}

__global__ void __launch_bounds__(THREADS) lstm_kernel(
    const float* __restrict__ x,     // [B, T]
    const float* __restrict__ Wx,    // [4*H]
    const float* __restrict__ bx,    // [4*H]
    const float* __restrict__ bh,    // [4*H]
    const bf16_t* __restrict__ W2,   // [4*H][H] bf16 (row j = gate-col, contiguous in k)
    const float* __restrict__ W_ph,  // [O, H]
    const float* __restrict__ b_ph,  // [O]
    float* __restrict__ out)         // [B, O]
{
    __shared__ bf16_t h_sh[16 * 256];   // h_t, bf16, XOR-swizzled
    __shared__ float  xf_sh[16 * 256];  // x tile [16][T]; reused as fp32 h_final at the end
    __shared__ float  wx_sh[1024];
    __shared__ float  bias_sh[1024];    // bx + bh

    const int tid  = threadIdx.x;
    const int wave = tid >> 6;
    const int lane = tid & 63;
    const int n    = lane & 15;   // col within 16-wide MFMA tile (also A-frag row)
    const int grp  = lane >> 4;   // 0..3
    const int b0   = blockIdx.x * BTILE;

    // stage x tile [16][256] (coalesced float4)
    {
        int r = tid >> 6;
        int c = (tid & 63) << 2;
        float4 v = *(const float4*)(x + (size_t)(b0 + r) * LSTM_T + c);
        *(float4*)(xf_sh + r * 256 + c) = v;
    }
    wx_sh[tid]   = Wx[tid];
    bias_sh[tid] = bx[tid] + bh[tid];
    // zero h_sh (8192 B = 2048 dwords)
    ((unsigned int*)h_sh)[tid]        = 0u;
    ((unsigned int*)h_sh)[tid + 1024] = 0u;
    __syncthreads();

    // per-lane constants hoisted out of the whole T loop
    const int hh = wave * 16 + n;   // this lane's hidden column
    float wxv[4], biv[4];
#pragma unroll
    for (int g = 0; g < 4; ++g) {
        wxv[g] = wx_sh[g * 256 + hh];
        biv[g] = bias_sh[g * 256 + hh];
    }
    // B-frag base: row j = g*256 + hh of W2, k-offset grp*8
    const bf16_t* wp = W2 + (size_t)hh * 256 + grp * 8;

    float c_st[4] = {0.f, 0.f, 0.f, 0.f};   // cell state, lives in C/D lane layout forever

    for (int t = 0; t < LSTM_T; ++t) {
        // A-frags: lane holds h[m=n][k = kk*32 + grp*8 .. +7]
        bf16x8 aF[8];
#pragma unroll
        for (int kk = 0; kk < 8; ++kk)
            aF[kk] = *(const bf16x8*)&h_sh[hsw(n, kk * 32 + grp * 8)];
        __syncthreads();   // A reads done -> h_sh free for overwrite

        f32x4 acc[4];
#pragma unroll
        for (int g = 0; g < 4; ++g) acc[g] = (f32x4){0.f, 0.f, 0.f, 0.f};

#pragma unroll
        for (int g = 0; g < 4; ++g) {
            const bf16_t* wg = wp + g * (256 * 256);
#pragma unroll
            for (int kk = 0; kk < 8; ++kk) {
                bf16x8 bF = *(const bf16x8*)(wg + kk * 32);
                acc[g] = __builtin_amdgcn_mfma_f32_16x16x32_bf16(aF[kk], bF, acc[g], 0, 0, 0);
            }
        }

        // pointwise: lane owns rows r = grp*4+q, col hh
        float hval[4];
#pragma unroll
        for (int q = 0; q < 4; ++q) {
            int r = grp * 4 + q;
            float xt = xf_sh[r * 256 + t];
            float z0 = acc[0][q] + xt * wxv[0] + biv[0];
            float z1 = acc[1][q] + xt * wxv[1] + biv[1];
            float z2 = acc[2][q] + xt * wxv[2] + biv[2];
            float z3 = acc[3][q] + xt * wxv[3] + biv[3];
            float gg = tanh_f(z0);
            float ii = sigmoid_f(z1);
            float ff = sigmoid_f(z2);
            float oo = sigmoid_f(z3);
            float cn = gg * ii + c_st[q] * ff;
            c_st[q] = cn;
            hval[q] = tanh_f(cn) * oo;
        }

        if (t < LSTM_T - 1) {
#pragma unroll
            for (int q = 0; q < 4; ++q)
                h_sh[hsw(grp * 4 + q, hh)] = (bf16_t)hval[q];
            __syncthreads();   // h_{t+1} visible for next iteration's A reads
        } else {
            __syncthreads();   // everyone done reading x tile
#pragma unroll
            for (int q = 0; q < 4; ++q)
                xf_sh[(grp * 4 + q) * 256 + hh] = hval[q];   // fp32 h_T
            __syncthreads();
        }
    }

    // fused output projection: out[b0+r][o] = h_T[r] . W_ph[o] + b_ph[o]
    if (tid < 16 * LSTM_O) {
        int r = tid & 15;
        int o = tid >> 4;
        const float* wrow = W_ph + o * 256;
        const float* hrow = xf_sh + r * 256;
        float s = 0.f;
#pragma unroll 4
        for (int k0 = 0; k0 < 256; ++k0) {
            int k = (k0 + r * 16) & 255;   // rotate start to dodge LDS bank conflicts
            s += hrow[k] * wrow[k];
        }
        out[(size_t)(b0 + r) * LSTM_O + o] = s + b_ph[o];
    }
}

extern "C" void kernel_launch(void* const* d_in, const int* in_sizes, int n_in,
                              void* d_out, int out_size, void* d_ws, size_t ws_size,
                              hipStream_t stream) {
    const float* x    = (const float*)d_in[0];
    const float* Wx   = (const float*)d_in[1];
    const float* bx   = (const float*)d_in[2];
    const float* Wh   = (const float*)d_in[3];
    const float* bh   = (const float*)d_in[4];
    const float* W_ph = (const float*)d_in[5];
    const float* b_ph = (const float*)d_in[6];
    float* out  = (float*)d_out;
    bf16_t* W2  = (bf16_t*)d_ws;   // 512 KB bf16 copy of Wh, rebuilt every call (ws is re-poisoned)

    cast_wh_kernel<<<256, 256, 0, stream>>>(Wh, W2);
    lstm_kernel<<<NBLK, THREADS, 0, stream>>>(x, Wx, bx, bh, W2, W_ph, b_ph, out);
}